// Round 6
// baseline (44.144 us; speedup 1.0000x reference)
//
#include <hip/hip_runtime.h>
#include <stdint.h>

#define NSAMP   1000
#define BATCH   16
#define NITEMS  2048
#define SPG     8                 // samples per workgroup (max racc = 8*4094 < 65535 -> u16)
#define NGROUPS (NSAMP / SPG)     // 125
#define T       256               // threads per block
#define EPT     8                 // elements per thread (T*EPT == NITEMS)
#define KB      2048              // buckets
#define HSZ     (KB + (KB >> 3))  // 2304 words: padded hist (9 words per 8 buckets)
#define SIGMA   0.1f

// padded hist address: i + i/8 -> lane stride 9 words (coprime with 32 banks)
__device__ __forceinline__ int ha(int i) { return i + (i >> 3); }

// Midpoint rank: rank2 = 2*prefix[bkt] + count[bkt] - 1  (== 2*rank + in-bucket
// midpoint offset). Noise sigma (~0.128) >> bucket width (~0.005), so an element's
// intra-bucket position is ~uniform iid per sample -> midpoint error is zero-mean
// and averages out over 1000 samples (removes the systematic arrival-order bias
// of the cursor-atomic scheme, which measured absmax 8.0).
__global__ __launch_bounds__(T, 7) void rank_kernel(const float* __restrict__ x,
                                                    const float* __restrict__ noise,
                                                    void* __restrict__ outbuf,
                                                    int use_ws) {
    __shared__ uint32_t histA[HSZ];   // 9 KB
    __shared__ uint32_t histB[HSZ];   // 9 KB (double buffer: zeroing folds into prefix phase)
    __shared__ float    scrf[8];
    __shared__ uint32_t scru[4];

    const int tid  = threadIdx.x;
    const int lane = tid & 63;
    const int wid  = tid >> 6;
    const int b    = blockIdx.y;
    const int g    = blockIdx.x;

    // x row -> registers
    float xr[EPT];
    {
        const float4* xv = reinterpret_cast<const float4*>(x + (size_t)b * NITEMS);
        float4 a0 = xv[tid * 2], a1 = xv[tid * 2 + 1];
        xr[0] = a0.x; xr[1] = a0.y; xr[2] = a0.z; xr[3] = a0.w;
        xr[4] = a1.x; xr[5] = a1.y; xr[6] = a1.z; xr[7] = a1.w;
    }
    uint32_t racc[EPT];   // accumulates 2x rank
    #pragma unroll
    for (int k = 0; k < EPT; ++k) racc[k] = 0;

    const float* nbase = noise + ((size_t)(g * SPG) * BATCH + b) * NITEMS;
    const size_t sstr  = (size_t)BATCH * NITEMS;

    // prefetch sample 0
    float4 n0, n1;
    {
        const float4* nv = reinterpret_cast<const float4*>(nbase);
        n0 = nv[tid * 2]; n1 = nv[tid * 2 + 1];
    }

    // zero both hist buffers (covered by the scale-phase barrier below)
    #pragma unroll
    for (int k = 0; k < 9; ++k) { histA[tid * 9 + k] = 0; histB[tid * 9 + k] = 0; }

    // ---- bucket scale: once per block, from sample 0 with 12.5% margin ----
    float vmin, sca;
    {
        float t[EPT];
        t[0] = n0.x; t[1] = n0.y; t[2] = n0.z; t[3] = n0.w;
        t[4] = n1.x; t[5] = n1.y; t[6] = n1.z; t[7] = n1.w;
        float mn = __fadd_rn(xr[0], __fmul_rn(SIGMA, t[0])), mx = mn;
        #pragma unroll
        for (int k = 1; k < EPT; ++k) {
            float v = __fadd_rn(xr[k], __fmul_rn(SIGMA, t[k]));
            mn = fminf(mn, v); mx = fmaxf(mx, v);
        }
        #pragma unroll
        for (int off = 32; off; off >>= 1) {
            mn = fminf(mn, __shfl_xor(mn, off));
            mx = fmaxf(mx, __shfl_xor(mx, off));
        }
        if (lane == 0) { scrf[wid] = mn; scrf[4 + wid] = mx; }
        __syncthreads();   // covers hist zeroing + scrf publish
        mn = fminf(fminf(scrf[0], scrf[1]), fminf(scrf[2], scrf[3]));
        mx = fmaxf(fmaxf(scrf[4], scrf[5]), fmaxf(scrf[6], scrf[7]));
        float span = mx - mn;
        vmin = mn - 0.125f * span;
        sca  = (span > 0.0f) ? ((float)KB / (1.25f * span)) : 0.0f;
    }

    uint32_t* cur = histA;
    uint32_t* nxt = histB;

    for (int ss = 0; ss < SPG; ++ss) {
        // ---- perturbed values (non-fused, matches f32 reference rounding) ----
        float v[EPT];
        v[0] = n0.x; v[1] = n0.y; v[2] = n0.z; v[3] = n0.w;
        v[4] = n1.x; v[5] = n1.y; v[6] = n1.z; v[7] = n1.w;
        #pragma unroll
        for (int k = 0; k < EPT; ++k) v[k] = __fadd_rn(xr[k], __fmul_rn(SIGMA, v[k]));

        // prefetch next sample (hides under LDS phases)
        if (ss + 1 < SPG) {
            const float4* nv = reinterpret_cast<const float4*>(nbase + (ss + 1) * sstr);
            n0 = nv[tid * 2]; n1 = nv[tid * 2 + 1];
        }

        // buckets (monotone in v; clamp handles rare out-of-margin samples)
        uint32_t bkt[EPT];
        #pragma unroll
        for (int k = 0; k < EPT; ++k) {
            float t = fmaxf((v[k] - vmin) * sca, 0.0f);
            uint32_t bb = (uint32_t)t;
            bkt[k] = bb < (KB - 1) ? bb : (KB - 1);
            atomicAdd(&cur[ha(bkt[k])], 1u);
        }
        __syncthreads();   // (a) histogram complete

        // ---- exclusive prefix scan; write packed (prefix | count<<16) ----
        uint32_t h[EPT], sum = 0;
        #pragma unroll
        for (int k = 0; k < EPT; ++k) { h[k] = cur[tid * 9 + k]; sum += h[k]; }
        uint32_t inc = sum;
        #pragma unroll
        for (int off = 1; off < 64; off <<= 1) {
            uint32_t t2 = (uint32_t)__shfl_up((int)inc, off);
            if (lane >= off) inc += t2;
        }
        if (lane == 63) scru[wid] = inc;
        __syncthreads();   // (b) wave totals published

        uint32_t woff = 0;
        for (int w = 0; w < wid; ++w) woff += scru[w];
        uint32_t run = woff + inc - sum;
        #pragma unroll
        for (int k = 0; k < EPT; ++k) {
            cur[tid * 9 + k] = run | (h[k] << 16);   // prefix lo16, count hi16
            run += h[k];
        }
        if (ss + 1 < SPG) {   // zero next buffer (its readers finished before (a))
            #pragma unroll
            for (int k = 0; k < 9; ++k) nxt[tid * 9 + k] = 0;
        }
        __syncthreads();   // (c) packed prefix published (+ next buffer zeroed)

        // ---- rank2 = 2*prefix + count - 1 (single LDS read per element) ----
        #pragma unroll
        for (int k = 0; k < EPT; ++k) {
            uint32_t w = cur[ha(bkt[k])];
            racc[k] += 2u * (w & 0xFFFFu) + (w >> 16) - 1u;
        }

        uint32_t* t = cur; cur = nxt; nxt = t;
    }

    if (use_ws) {
        // pack 8 x u16 partial rank2-sums -> one uint4, coalesced: part16[g][b][i]
        uint32_t p0 = (racc[0] & 0xFFFFu) | (racc[1] << 16);
        uint32_t p1 = (racc[2] & 0xFFFFu) | (racc[3] << 16);
        uint32_t p2 = (racc[4] & 0xFFFFu) | (racc[5] << 16);
        uint32_t p3 = (racc[6] & 0xFFFFu) | (racc[7] << 16);
        uint16_t* part16 = (uint16_t*)outbuf;
        uint4* pp = reinterpret_cast<uint4*>(part16 + ((size_t)g * BATCH + b) * NITEMS);
        pp[tid] = make_uint4(p0, p1, p2, p3);
    } else {
        uint32_t* gacc = (uint32_t*)outbuf;
        #pragma unroll
        for (int k = 0; k < EPT; ++k)
            atomicAdd(&gacc[(size_t)b * NITEMS + tid * EPT + k], racc[k]);
    }
}

// partials: u16 part[g][16][2048] of 2x-rank sums; sum over 125 groups, /2000.
__global__ __launch_bounds__(T) void finalize_ws(const uint32_t* __restrict__ part32,
                                                 float* __restrict__ out) {
    const int j = blockIdx.x * blockDim.x + threadIdx.x;   // 16384 threads
    const int W = BATCH * NITEMS / 2;                       // 16384 words per group
    uint32_t lo = 0, hi = 0;
    #pragma unroll 1
    for (int g = 0; g < NGROUPS; g += 5) {                  // 25 iters x 5 indep loads
        uint32_t w0 = part32[(size_t)(g    ) * W + j];
        uint32_t w1 = part32[(size_t)(g + 1) * W + j];
        uint32_t w2 = part32[(size_t)(g + 2) * W + j];
        uint32_t w3 = part32[(size_t)(g + 3) * W + j];
        uint32_t w4 = part32[(size_t)(g + 4) * W + j];
        lo += (w0 & 0xFFFFu) + (w1 & 0xFFFFu) + (w2 & 0xFFFFu)
            + (w3 & 0xFFFFu) + (w4 & 0xFFFFu);
        hi += (w0 >> 16) + (w1 >> 16) + (w2 >> 16) + (w3 >> 16) + (w4 >> 16);
    }
    const float s = 1.0f / (2.0f * NSAMP);
    reinterpret_cast<float2*>(out)[j] = make_float2((float)lo * s, (float)hi * s);
}

__global__ __launch_bounds__(T) void finalize_atomic(uint32_t* __restrict__ g,
                                                     float* __restrict__ out) {
    int i = blockIdx.x * blockDim.x + threadIdx.x;
    if (i < BATCH * NITEMS) {
        uint32_t v = g[i];
        out[i] = (float)v / (2.0f * NSAMP);
    }
}

extern "C" void kernel_launch(void* const* d_in, const int* in_sizes, int n_in,
                              void* d_out, int out_size, void* d_ws, size_t ws_size,
                              hipStream_t stream) {
    const float* x     = (const float*)d_in[0];
    const float* noise = (const float*)d_in[1];
    const size_t need  = (size_t)NGROUPS * BATCH * NITEMS * sizeof(uint16_t);  // 8.2 MB
    dim3 grid(NGROUPS, BATCH, 1);
    int n = BATCH * NITEMS;

    if (ws_size >= need) {
        rank_kernel<<<grid, T, 0, stream>>>(x, noise, d_ws, 1);
        finalize_ws<<<(n / 2) / T, T, 0, stream>>>((const uint32_t*)d_ws, (float*)d_out);
    } else {
        hipMemsetAsync(d_out, 0, (size_t)n * sizeof(uint32_t), stream);
        rank_kernel<<<grid, T, 0, stream>>>(x, noise, d_out, 0);
        finalize_atomic<<<(n + T - 1) / T, T, 0, stream>>>((uint32_t*)d_out, (float*)d_out);
    }
}